// Round 14
// baseline (368.587 us; speedup 1.0000x reference)
//
#include <hip/hip_runtime.h>
#include <hip/hip_bf16.h>
#include <math.h>

#define NEG_SLOPE 0.2f

typedef __attribute__((ext_vector_type(4))) float f32x4;
typedef __attribute__((ext_vector_type(8))) short bf16x8;
typedef __attribute__((ext_vector_type(4))) short bf16x4;

__device__ __forceinline__ float leaky(float x) { return x > 0.f ? x : NEG_SLOPE * x; }

__device__ __forceinline__ unsigned short bf_hi(float x) {
  return (unsigned short)(__float_as_uint(x) >> 16);  // truncation split (exact residual)
}

__device__ __forceinline__ unsigned short bf_rne(float x) {
  unsigned u = __float_as_uint(x);
  return (unsigned short)((u + 0x7FFFu + ((u >> 16) & 1u)) >> 16);  // round-nearest-even
}

// order-preserving float<->uint encoding for atomicMax over signed floats
__device__ __forceinline__ unsigned fenc(float f) {
  int b = __float_as_int(f);
  return (b < 0) ? ~(unsigned)b : ((unsigned)b | 0x80000000u);
}
__device__ __forceinline__ float fdec(unsigned u) {
  int b = (u & 0x80000000u) ? (int)(u & 0x7FFFFFFFu) : (int)(~u);
  return __int_as_float(b);
}

// ---------------- CSR build: bucket-local, fixed-capacity staging ----------------

#define BIN_CHUNK 4096
#define BCAP 8192

__global__ void k_curinit(int* __restrict__ cursor, int NB, unsigned* __restrict__ maxSenc) {
  int i = blockIdx.x * blockDim.x + threadIdx.x;
  if (i < NB) cursor[i] = i * BCAP;
  if (i < 2) maxSenc[i] = 0u;               // encodes -inf-ish; overwritten by gemm
}

// stage edges bucket-contiguously; entry = (src | dstlow<<24, weight_bits)
__device__ void bin_body(int bid, const int* __restrict__ ei, const float* __restrict__ ew,
                         int E, int N, int* __restrict__ cursor,
                         int2* __restrict__ staged, int NB) {
  __shared__ int lhist[512];
  __shared__ int lbase[512];
  int tid = threadIdx.x;
  int start = bid * BIN_CHUNK;
  int NT = E + N;
  int srcv[16], dstv[16]; float wv[16];
#pragma unroll
  for (int j = 0; j < 16; j++) {
    int e = start + j * 256 + tid;       // coalesced
    int s = 0, d = -1; float w = 0.f;
    if (e < NT) {
      if (e < E) { s = ei[e]; d = ei[E + e]; w = ew[e]; }
      else       { s = d = e - E; w = 1.f; }   // self-loop
    }
    srcv[j] = s; dstv[j] = d; wv[j] = w;
  }
  for (int b = tid; b < NB; b += 256) lhist[b] = 0;
  __syncthreads();
#pragma unroll
  for (int j = 0; j < 16; j++)
    if (dstv[j] >= 0) atomicAdd(&lhist[dstv[j] >> 8], 1);
  __syncthreads();
  for (int b = tid; b < NB; b += 256) {
    int n = lhist[b];
    lbase[b] = (n > 0) ? atomicAdd(&cursor[b], n) : 0;
    lhist[b] = 0;
  }
  __syncthreads();
#pragma unroll
  for (int j = 0; j < 16; j++) {
    if (dstv[j] >= 0) {
      int bkt = dstv[j] >> 8;
      int off = atomicAdd(&lhist[bkt], 1);          // LDS cursor
      staged[lbase[bkt] + off] =
          make_int2(srcv[j] | ((dstv[j] & 255) << 24), __float_as_int(wv[j]));
    }
  }
}

// totals from cursor deltas -> exclusive scan -> packed bases
__global__ void k_bscan(const int* __restrict__ cursor, int NB, int NT, int N,
                        int* __restrict__ bbase, int* __restrict__ rp) {
  __shared__ int sm[1024];
  for (int j = threadIdx.x; j < NB; j += blockDim.x)
    sm[j] = cursor[j] - j * BCAP;                  // bucket total
  __syncthreads();
  if (threadIdx.x == 0) {
    int run = 0;
    for (int j = 0; j < NB; j++) { int t = sm[j]; sm[j] = run; run += t; }
    sm[NB] = run;                                  // == NT
  }
  __syncthreads();
  for (int j = threadIdx.x; j <= NB; j += blockDim.x) bbase[j] = sm[j];
  if (threadIdx.x == 0) rp[N] = NT;
}

// one block per bucket: LDS count -> scan -> rp -> LDS-cursor scatter to packed csr
__global__ __launch_bounds__(256)
void k_finalize(const int2* __restrict__ staged, const int* __restrict__ bbase,
                int N, int* __restrict__ rp, int2* __restrict__ csr) {
  __shared__ int cnt[256];
  __shared__ int sm[256];
  int b = blockIdx.x, tid = threadIdx.x;
  int sbase = b * BCAP;
  int cbase = bbase[b];
  int size = bbase[b + 1] - cbase;
  cnt[tid] = 0;
  __syncthreads();
  for (int i = tid; i < size; i += 256) {
    int2 v = staged[sbase + i];
    atomicAdd(&cnt[((unsigned)v.x) >> 24], 1);
  }
  __syncthreads();
  int s = cnt[tid];
  sm[tid] = s;
  __syncthreads();
  for (int off = 1; off < 256; off <<= 1) {    // Hillis-Steele inclusive scan
    int v = sm[tid];
    int add = (tid >= off) ? sm[tid - off] : 0;
    __syncthreads();
    sm[tid] = v + add;
    __syncthreads();
  }
  int excl = sm[tid] - s;
  int node = (b << 8) + tid;
  if (node < N) rp[node] = cbase + excl;
  cnt[tid] = excl;                              // becomes the scatter cursor
  __syncthreads();
  for (int i = tid; i < size; i += 256) {
    int2 v = staged[sbase + i];
    int dlow = ((unsigned)v.x) >> 24;
    int pos = cbase + atomicAdd(&cnt[dlow], 1); // LDS atomic
    csr[pos] = make_int2(v.x & 0x00FFFFFF, v.y);
  }
}

// ---------------- W pre-conversion (both layers in one launch) ----------------
__global__ __launch_bounds__(256)
void k_wprep(const float* __restrict__ W1, int K1, int M1,
             unsigned short* __restrict__ whi1, unsigned short* __restrict__ wlo1,
             const float* __restrict__ W2, int K2, int M2,
             unsigned short* __restrict__ whi2, unsigned short* __restrict__ wlo2) {
  int idx = blockIdx.x * 256 + threadIdx.x;
  const float* W; int K, Mout; unsigned short *whi, *wlo;
  if (idx < K1 * 64) { W = W1; K = K1; Mout = M1; whi = whi1; wlo = wlo1; }
  else { idx -= K1 * 64; if (idx >= K2 * 64) return;
         W = W2; K = K2; Mout = M2; whi = whi2; wlo = wlo2; }
  int k = idx >> 6, n = idx & 63;
  float v = (n < Mout) ? W[(size_t)k * Mout + n] : 0.f;
  unsigned short h = bf_hi(v);
  float hf = __uint_as_float((unsigned)h << 16);
  unsigned short l = bf_hi(v - hf);
  int kc = k >> 5, kk = k & 31, quad = kk >> 3, j = kk & 7;
  int ct = n >> 4, nn = n & 15;
  int off = (((kc * 4 + ct) * 64) + quad * 16 + nn) * 8 + j;
  whi[off] = h; wlo[off] = l;
}

// ---------------- MFMA GEMM (split-bf16) + fused scores + global S-max ----------------
__device__ void gemm_body(int bid, const float* __restrict__ X, int K,
                          const unsigned short* __restrict__ WHI,
                          const unsigned short* __restrict__ WLO,
                          const float* __restrict__ ASRC, const float* __restrict__ ADST,
                          int Mout, float* __restrict__ Hf, unsigned short* __restrict__ Hb,
                          int ldH, float* __restrict__ S, float* __restrict__ D,
                          unsigned* __restrict__ maxSenc, int N) {
  __shared__ __align__(16) unsigned short xhi[2048], xlo[2048];
  __shared__ __align__(16) unsigned short whs[2048], wls[2048];
  __shared__ unsigned smaxl;
  int tid = threadIdx.x;
  int lane = tid & 63, w = tid >> 6;
  int rowBase = bid * 64;

  f32x4 acc[4];
#pragma unroll
  for (int c = 0; c < 4; c++) acc[c] = (f32x4){0.f, 0.f, 0.f, 0.f};

  int q0 = tid, q1 = tid + 256;
  int row0 = q0 >> 3, k40 = (q0 & 7) << 2;
  int row1 = q1 >> 3, k41 = (q1 & 7) << 2;
  int xo0 = (((row0 >> 4) * 64) + (k40 >> 3) * 16 + (row0 & 15)) * 8 + (k40 & 7);
  int xo1 = (((row1 >> 4) * 64) + (k41 >> 3) * 16 + (row1 & 15)) * 8 + (k41 & 7);
  int grow0 = rowBase + row0, grow1 = rowBase + row1;

  int nch = K >> 5;
  f32x4 xr0, xr1; bf16x8 wh, wl;

  xr0 = (f32x4){0.f, 0.f, 0.f, 0.f}; xr1 = xr0;
  if (grow0 < N) xr0 = *(const f32x4*)&X[(size_t)grow0 * K + k40];
  if (grow1 < N) xr1 = *(const f32x4*)&X[(size_t)grow1 * K + k41];
  wh = *(const bf16x8*)(WHI + tid * 8);
  wl = *(const bf16x8*)(WLO + tid * 8);

  for (int kc = 0; kc < nch; kc++) {
    bf16x4 h4, l4;
#pragma unroll
    for (int i = 0; i < 4; i++) {
      unsigned short h = bf_hi(xr0[i]);
      float hf = __uint_as_float((unsigned)h << 16);
      h4[i] = (short)h; l4[i] = (short)bf_hi(xr0[i] - hf);
    }
    *(bf16x4*)(xhi + xo0) = h4; *(bf16x4*)(xlo + xo0) = l4;
#pragma unroll
    for (int i = 0; i < 4; i++) {
      unsigned short h = bf_hi(xr1[i]);
      float hf = __uint_as_float((unsigned)h << 16);
      h4[i] = (short)h; l4[i] = (short)bf_hi(xr1[i] - hf);
    }
    *(bf16x4*)(xhi + xo1) = h4; *(bf16x4*)(xlo + xo1) = l4;
    *(bf16x8*)(whs + tid * 8) = wh;
    *(bf16x8*)(wls + tid * 8) = wl;
    __syncthreads();

    if (kc + 1 < nch) {
      int kb = (kc + 1) << 5;
      xr0 = (f32x4){0.f, 0.f, 0.f, 0.f}; xr1 = xr0;
      if (grow0 < N) xr0 = *(const f32x4*)&X[(size_t)grow0 * K + kb + k40];
      if (grow1 < N) xr1 = *(const f32x4*)&X[(size_t)grow1 * K + kb + k41];
      wh = *(const bf16x8*)(WHI + (size_t)(kc + 1) * 2048 + tid * 8);
      wl = *(const bf16x8*)(WLO + (size_t)(kc + 1) * 2048 + tid * 8);
    }

    bf16x8 ah = *(const bf16x8*)(xhi + (w * 64 + lane) * 8);
    bf16x8 al = *(const bf16x8*)(xlo + (w * 64 + lane) * 8);
#pragma unroll
    for (int c = 0; c < 4; c++) {
      bf16x8 bh = *(const bf16x8*)(whs + (c * 64 + lane) * 8);
      bf16x8 bl = *(const bf16x8*)(wls + (c * 64 + lane) * 8);
      acc[c] = __builtin_amdgcn_mfma_f32_16x16x32_bf16(ah, bh, acc[c], 0, 0, 0);
      acc[c] = __builtin_amdgcn_mfma_f32_16x16x32_bf16(ah, bl, acc[c], 0, 0, 0);
      acc[c] = __builtin_amdgcn_mfma_f32_16x16x32_bf16(al, bh, acc[c], 0, 0, 0);
    }
    __syncthreads();
  }

  if (tid == 0) smaxl = 0u;
  __syncthreads();

  int nn = lane & 15, quad = lane >> 4;
  float as_[4], ad_[4];
#pragma unroll
  for (int c = 0; c < 4; c++) {
    int col = c * 16 + nn;
    as_[c] = (col < Mout) ? ASRC[col] : 0.f;
    ad_[c] = (col < Mout) ? ADST[col] : 0.f;
  }
  float psmax = -1e30f;
  bool anyrow = false;
#pragma unroll
  for (int r = 0; r < 4; r++) {
    int grow = rowBase + w * 16 + quad * 4 + r;
    float ps = 0.f, pd = 0.f;
#pragma unroll
    for (int c = 0; c < 4; c++) {
      float v = acc[c][r];
      int col = c * 16 + nn;
      if (grow < N && col < Mout) {
        if (Hb) Hb[(size_t)grow * ldH + col] = bf_rne(v);
        else    Hf[(size_t)grow * ldH + col] = v;
      }
      ps += v * as_[c]; pd += v * ad_[c];
    }
#pragma unroll
    for (int off = 1; off < 16; off <<= 1) {
      ps += __shfl_xor(ps, off);
      pd += __shfl_xor(pd, off);
    }
    if (nn == 0 && grow < N) {
      S[grow] = ps; D[grow] = pd;
      psmax = fmaxf(psmax, ps); anyrow = true;
    }
  }
  if (anyrow) atomicMax(&smaxl, fenc(psmax));
  __syncthreads();
  if (tid == 0) atomicMax(maxSenc, smaxl);
}

// fused: gemm layer-1 blocks + bin blocks in one launch (independent work overlaps)
__global__ __launch_bounds__(256)
void k_fused_g1bin(const float* __restrict__ X, int K,
                   const unsigned short* __restrict__ WHI, const unsigned short* __restrict__ WLO,
                   const float* __restrict__ ASRC, const float* __restrict__ ADST, int Mout,
                   unsigned short* __restrict__ Hb, int ldH,
                   float* __restrict__ S, float* __restrict__ D,
                   unsigned* __restrict__ maxSenc, int N, int gblocks,
                   const int* __restrict__ ei, const float* __restrict__ ew, int E,
                   int* __restrict__ cursor, int2* __restrict__ staged, int NB) {
  if ((int)blockIdx.x < gblocks)
    gemm_body(blockIdx.x, X, K, WHI, WLO, ASRC, ADST, Mout,
              (float*)nullptr, Hb, ldH, S, D, maxSenc, N);
  else
    bin_body(blockIdx.x - gblocks, ei, ew, E, N, cursor, staged, NB);
}

__global__ __launch_bounds__(256)
void k_gemm(const float* __restrict__ X, int K,
            const unsigned short* __restrict__ WHI, const unsigned short* __restrict__ WLO,
            const float* __restrict__ ASRC, const float* __restrict__ ADST, int Mout,
            float* __restrict__ Hf, int ldH, float* __restrict__ S, float* __restrict__ D,
            unsigned* __restrict__ maxSenc, int N) {
  gemm_body(blockIdx.x, X, K, WHI, WLO, ASRC, ADST, Mout,
            Hf, (unsigned short*)nullptr, ldH, S, D, maxSenc, N);
}

// ---------------- fused aggregation: global-max softmax, 4 nodes per wave ----------------
// M = leaky(maxS + dd) >= every edge score of this node (leaky monotone, shift-invariant
// softmax => exact). No online rescale: shorter critical path, ~15% fewer VALU issues.
// H-row gathers predicated on fl < F4 (R11 lesson: dead lanes still fetch).
template <bool BF16>
__global__ __launch_bounds__(256)
void k_agg_fused(const int* __restrict__ rp, const int2* __restrict__ csr,
                 const float* __restrict__ S, const float* __restrict__ D,
                 const unsigned* __restrict__ maxSenc,
                 const void* __restrict__ HinV, int ldh,
                 float* __restrict__ Out, int F4, int ldo, int do_relu, int N) {
  int gw = (blockIdx.x * blockDim.x + threadIdx.x) >> 6;
  int lane = threadIdx.x & 63;
  int sub = lane >> 4, fl = lane & 15;
  int node = gw * 4 + sub;
  bool active = node < N;
  bool fless = fl < F4;
  int b = 0, e = 1; float dd = 0.f;
  if (active) { b = rp[node]; e = rp[node + 1]; dd = D[node]; }
  float M = leaky(fdec(*maxSenc) + dd);            // per-node constant upper bound
  float den = 0.f;
  f32x4 acc = (f32x4){0.f, 0.f, 0.f, 0.f};

  int need = e - b;
  need = max(need, __shfl_xor(need, 16));
  need = max(need, __shfl_xor(need, 32));
  int iters = (need + 3) >> 2;
  int last = e - 1;

  int t = b;
  for (int it = 0; it < iters; it++, t += 4) {
    int  idx[4]; float wgt[4], sv[4], ex[4]; f32x4 hv[4];
#pragma unroll
    for (int j = 0; j < 4; j++) {
      int tj = t + j < e ? t + j : last;            // tail re-reads warm lines
      int2 p = csr[tj];                             // 16-lane broadcast load
      idx[j] = p.x;
      wgt[j] = (t + j < e) ? __int_as_float(p.y) : 0.f;
    }
#pragma unroll
    for (int j = 0; j < 4; j++) sv[j] = S[idx[j]];
#pragma unroll
    for (int j = 0; j < 4; j++) {
      hv[j] = (f32x4){0.f, 0.f, 0.f, 0.f};
      if (fless) {                                   // exec-masked: no fetch for fl>=F4
        if (BF16) {
          const unsigned short* Hbp = (const unsigned short*)HinV;
          ushort4 uv = *(const ushort4*)(Hbp + (size_t)idx[j] * ldh + (fl << 2));
          hv[j][0] = __uint_as_float((unsigned)uv.x << 16);
          hv[j][1] = __uint_as_float((unsigned)uv.y << 16);
          hv[j][2] = __uint_as_float((unsigned)uv.z << 16);
          hv[j][3] = __uint_as_float((unsigned)uv.w << 16);
        } else {
          const float* Hfp = (const float*)HinV;
          hv[j] = *(const f32x4*)&Hfp[(size_t)idx[j] * ldh + (fl << 2)];
        }
      }
    }
#pragma unroll
    for (int j = 0; j < 4; j++)
      ex[j] = (t + j < e) ? __expf(leaky(sv[j] + dd) - M) : 0.f;
    den += (ex[0] + ex[1]) + (ex[2] + ex[3]);
    acc += hv[0] * (ex[0] * wgt[0]) + hv[1] * (ex[1] * wgt[1])
         + hv[2] * (ex[2] * wgt[2]) + hv[3] * (ex[3] * wgt[3]);
  }

  if (active && fless) {
    float inv = 1.0f / fmaxf(den, 1e-16f);
    f32x4 o = acc * inv;
    if (do_relu) {
#pragma unroll
      for (int j = 0; j < 4; j++) o[j] = fmaxf(o[j], 0.f);
    }
    *(f32x4*)&Out[(size_t)node * ldo + (fl << 2)] = o;
  }
}

// ---------------- launch ----------------
extern "C" void kernel_launch(void* const* d_in, const int* in_sizes, int n_in,
                              void* d_out, int out_size, void* d_ws, size_t ws_size,
                              hipStream_t stream) {
  const float* x   = (const float*)d_in[0];
  const int*   ei  = (const int*)d_in[1];
  const float* ew  = (const float*)d_in[2];
  const float* W1  = (const float*)d_in[3];
  const float* a1s = (const float*)d_in[4];
  const float* a1d = (const float*)d_in[5];
  const float* W2  = (const float*)d_in[6];
  const float* a2s = (const float*)d_in[7];
  const float* a2d = (const float*)d_in[8];

  const int HID = in_sizes[4];            // 64
  const int NC  = in_sizes[7];            // 40
  const int FIN = in_sizes[3] / HID;      // 256
  const int N   = in_sizes[0] / FIN;      // 100000
  const int E   = in_sizes[2];            // 1600000
  const int NT  = E + N;
  const int NB  = (N + 255) >> 8;         // 391 buckets
  float* out = (float*)d_out;

  char* wsb = (char*)d_ws;
  size_t off = 0;
  auto alloc = [&](size_t bytes) -> char* {
    char* p = wsb + off;
    off += (bytes + 255) & ~(size_t)255;
    return p;
  };
  unsigned short* h1b = (unsigned short*)alloc((size_t)N * 64 * 2);  // bf16 gather image
  float* h2     = (float*)alloc((size_t)N * 64 * 4);
  float* g2     = (float*)alloc((size_t)N * 40 * 4);
  float* S      = (float*)alloc((size_t)N * 4);
  float* D      = (float*)alloc((size_t)N * 4);
  int*   rp     = (int*)alloc((size_t)(N + 1) * 4);
  int*   bbase  = (int*)alloc((size_t)(NB + 1) * 4);
  int*   cursor = (int*)alloc((size_t)NB * 4);
  unsigned* maxSenc = (unsigned*)alloc(256);
  int2*  csr    = (int2*)alloc((size_t)NT * 8);
  int2*  staged = (int2*)alloc((size_t)NB * BCAP * 8);
  unsigned short* whi1 = (unsigned short*)alloc((size_t)FIN * 64 * 2);
  unsigned short* wlo1 = (unsigned short*)alloc((size_t)FIN * 64 * 2);
  unsigned short* whi2 = (unsigned short*)alloc((size_t)HID * 64 * 2);
  unsigned short* wlo2 = (unsigned short*)alloc((size_t)HID * 64 * 2);
  (void)ws_size; (void)n_in; (void)out_size;

  const int ebins = (NT + BIN_CHUNK - 1) / BIN_CHUNK;
  const int gblocks = (N + 63) / 64;
  const int ablocks = (N + 15) / 16;      // 16 nodes per 256-thread block
  const int wtot = (FIN + HID) * 64;

  hipLaunchKernelGGL(k_curinit, dim3((NB + 255) / 256), dim3(256), 0, stream,
                     cursor, NB, maxSenc);
  hipLaunchKernelGGL(k_wprep, dim3((wtot + 255) / 256), dim3(256), 0, stream,
                     W1, FIN, HID, whi1, wlo1, W2, HID, NC, whi2, wlo2);

  // ---- fused: gemm1 (h1b bf16, scores, maxS[0]) + bin (independent) ----
  hipLaunchKernelGGL(k_fused_g1bin, dim3(gblocks + ebins), dim3(256), 0, stream,
                     x, FIN, whi1, wlo1, a1s, a1d, HID, h1b, 64, S, D, maxSenc, N,
                     gblocks, ei, ew, E, cursor, staged, NB);
  hipLaunchKernelGGL(k_bscan, dim3(1), dim3(256), 0, stream, cursor, NB, NT, N, bbase, rp);
  hipLaunchKernelGGL(k_finalize, dim3(NB), dim3(256), 0, stream, staged, bbase, N, rp, csr);

  // ---- layer 1 aggregate -> h2 (ReLU) ----
  hipLaunchKernelGGL((k_agg_fused<true>), dim3(ablocks), dim3(256), 0, stream,
                     rp, csr, S, D, maxSenc + 0, (const void*)h1b, 64, h2, 16, 64, 1, N);

  // ---- layer 2: g2(f32, ld 40) = h2@W2, scores, maxS[1]; aggregate -> out ----
  hipLaunchKernelGGL(k_gemm, dim3(gblocks), dim3(256), 0, stream,
                     h2, HID, whi2, wlo2, a2s, a2d, NC, g2, 40, S, D, maxSenc + 1, N);
  hipLaunchKernelGGL((k_agg_fused<false>), dim3(ablocks), dim3(256), 0, stream,
                     rp, csr, S, D, maxSenc + 1, (const void*)g2, 40, out, 10, NC, 0, N);
}